// Round 4
// baseline (64.764 us; speedup 1.0000x reference)
//
#include <hip/hip_runtime.h>
#include <hip/hip_bf16.h>

#define NEG 0.2f
#define LOG2E 1.4426950408889634f

typedef __attribute__((ext_vector_type(8))) short bf16x8;
typedef __attribute__((ext_vector_type(4))) float f32x4;
typedef __attribute__((ext_vector_type(4))) int int4v;

__device__ __forceinline__ float lrelu(float t){ return fmaxf(t, NEG * t); }
__device__ __forceinline__ float fast_exp2(float x){
  float r; asm("v_exp_f32 %0, %1" : "=v"(r) : "v"(x)); return r;
}
__device__ __forceinline__ unsigned short f2bf(float f){   // RNE
  union { float f; unsigned int u; } v; v.f = f;
  unsigned int r = v.u + 0x7FFFu + ((v.u >> 16) & 1u);
  return (unsigned short)(r >> 16);
}

// ---------------- K0: Wt[o][k] = bf16(W[k][o]), once ----------------
__global__ __launch_bounds__(256) void k0_wt(const float* __restrict__ W,
                                             unsigned short* __restrict__ Wt){
  __shared__ __align__(16) unsigned short wl[128*136];
  const int t = threadIdx.x;
  {
    const int k = t >> 1, oh = (t & 1) * 64;
#pragma unroll 8
    for (int e = 0; e < 64; ++e)
      wl[(oh + e)*136 + k] = f2bf(W[k*128 + oh + e]);
  }
  __syncthreads();
  {
    const int o = t >> 1, ks = (t & 1) * 64;
#pragma unroll
    for (int g = 0; g < 8; ++g){
      int4v v = *(const int4v*)(wl + o*136 + ks + g*8);
      *(int4v*)(Wt + o*128 + ks + g*8) = v;
    }
  }
}

// ---------------- K1: h^T via MFMA + scaled s_src/s_dst + ht store ----------------
// grid 512 = 8b x 64 row-tiles (32 rows); block 256 = 4 waves, wave w owns o-range w*32..w*32+31.
// mfma(A=Wt[o][k], B=x[i][k]) -> D[o][i]  (ht layout directly)
__global__ __launch_bounds__(256) void k1_fused(const float* __restrict__ x,
                                                const unsigned short* __restrict__ Wt,
                                                const float* __restrict__ a,
                                                unsigned short* __restrict__ ht,
                                                float* __restrict__ ssrcL,
                                                float* __restrict__ sdstL){
  __shared__ __align__(16) unsigned short wtl[128*136];  // Wt [o][k] padded
  __shared__ __align__(16) unsigned short xl[32*136];    // x bf16 [i][k] padded
  __shared__ __align__(16) unsigned short tlw[128*34];   // transpose-out [o][j]
  __shared__ float sred[2][4][2][16];
  const int t = threadIdx.x;
  const int bx = blockIdx.x;                 // b*64 + jt
  const int b  = bx >> 6;
  const int jt = bx & 63;
  const long rowbase = (long)bx * 32;
  {
    const int o = t >> 1, seg = (t & 1) * 64;
    const int4v* src = (const int4v*)(Wt + o*128 + seg);
    int4v* dst = (int4v*)(wtl + o*136 + seg);
#pragma unroll
    for (int g = 0; g < 8; ++g) dst[g] = src[g];
  }
  {
    const int i = t >> 3, ks = (t & 7) * 16;
    const f32x4* src = (const f32x4*)(x + (rowbase + i)*128 + ks);
    unsigned int q[8];
#pragma unroll
    for (int g = 0; g < 4; ++g){
      f32x4 v = src[g];
      q[g*2]   = (unsigned)f2bf(v[0]) | ((unsigned)f2bf(v[1]) << 16);
      q[g*2+1] = (unsigned)f2bf(v[2]) | ((unsigned)f2bf(v[3]) << 16);
    }
    int4v* dst = (int4v*)(xl + i*136 + ks);
    dst[0] = *(int4v*)&q[0];
    dst[1] = *(int4v*)&q[4];
  }
  __syncthreads();
  const int w = t >> 6, lane = t & 63, lr = lane & 15, hi = lane >> 4;
  f32x4 zro = {0.f, 0.f, 0.f, 0.f};
  f32x4 acc00 = zro, acc01 = zro, acc10 = zro, acc11 = zro;
#pragma unroll
  for (int ks = 0; ks < 4; ++ks){
    const bf16x8 a0 = *(const bf16x8*)(wtl + (w*32      + lr)*136 + ks*32 + hi*8);
    const bf16x8 a1 = *(const bf16x8*)(wtl + (w*32 + 16 + lr)*136 + ks*32 + hi*8);
    const bf16x8 b0 = *(const bf16x8*)(xl + (     lr)*136 + ks*32 + hi*8);
    const bf16x8 b1 = *(const bf16x8*)(xl + (16 + lr)*136 + ks*32 + hi*8);
    acc00 = __builtin_amdgcn_mfma_f32_16x16x32_bf16(a0, b0, acc00, 0, 0, 0);
    acc01 = __builtin_amdgcn_mfma_f32_16x16x32_bf16(a0, b1, acc01, 0, 0, 0);
    acc10 = __builtin_amdgcn_mfma_f32_16x16x32_bf16(a1, b0, acc10, 0, 0, 0);
    acc11 = __builtin_amdgcn_mfma_f32_16x16x32_bf16(a1, b1, acc11, 0, 0, 0);
  }
  // s partials: lane holds h[o = w*32+og*16+hi*4+q][i = ig*16+lr]
  {
    const f32x4 as0 = *(const f32x4*)(a +       w*32      + hi*4);
    const f32x4 as1 = *(const f32x4*)(a +       w*32 + 16 + hi*4);
    const f32x4 ad0 = *(const f32x4*)(a + 128 + w*32      + hi*4);
    const f32x4 ad1 = *(const f32x4*)(a + 128 + w*32 + 16 + hi*4);
    float ps0, ps1, pd0, pd1;
    {
      f32x4 u = acc00*as0 + acc10*as1;  ps0 = u[0]+u[1]+u[2]+u[3];
      f32x4 v = acc01*as0 + acc11*as1;  ps1 = v[0]+v[1]+v[2]+v[3];
      f32x4 p = acc00*ad0 + acc10*ad1;  pd0 = p[0]+p[1]+p[2]+p[3];
      f32x4 r = acc01*ad0 + acc11*ad1;  pd1 = r[0]+r[1]+r[2]+r[3];
    }
#pragma unroll
    for (int off = 16; off <= 32; off <<= 1){
      ps0 += __shfl_xor(ps0, off); ps1 += __shfl_xor(ps1, off);
      pd0 += __shfl_xor(pd0, off); pd1 += __shfl_xor(pd1, off);
    }
    if (hi == 0){
      sred[0][w][0][lr] = ps0; sred[0][w][1][lr] = ps1;
      sred[1][w][0][lr] = pd0; sred[1][w][1][lr] = pd1;
    }
  }
  // transpose h -> tlw (bf16)
#pragma unroll
  for (int q = 0; q < 4; ++q){
    tlw[(w*32      + hi*4 + q)*34      + lr] = f2bf(acc00[q]);
    tlw[(w*32      + hi*4 + q)*34 + 16 + lr] = f2bf(acc01[q]);
    tlw[(w*32 + 16 + hi*4 + q)*34      + lr] = f2bf(acc10[q]);
    tlw[(w*32 + 16 + hi*4 + q)*34 + 16 + lr] = f2bf(acc11[q]);
  }
  __syncthreads();
  {
    const int o = t >> 1, jseg = (t & 1) * 16;
    const unsigned int* src = (const unsigned int*)(tlw + o*34 + jseg);
    unsigned int p[8];
#pragma unroll
    for (int g = 0; g < 8; ++g) p[g] = src[g];
    unsigned short* dst = ht + (long)b*262144 + (long)o*2048 + jt*32 + jseg;
    ((int4v*)dst)[0] = *(int4v*)&p[0];
    ((int4v*)dst)[1] = *(int4v*)&p[4];
  }
  if (t < 64){
    const int sel = t >> 5, jl = t & 31;
    const int ig = jl >> 4, l2 = jl & 15;
    const float s = sred[sel][0][ig][l2] + sred[sel][1][ig][l2]
                  + sred[sel][2][ig][l2] + sred[sel][3][ig][l2];
    if (sel == 0) ssrcL[rowbase + jl] = s * LOG2E;
    else          sdstL[rowbase + jl] = s * LOG2E;
  }
}

// ---------------- K2: per-row C_i = m_L + log2(sum_j 2^(lrelu(siL+sjL)-m_L)) ----------------
__global__ __launch_bounds__(256) void k2_ml(const float* __restrict__ ssrcL,
                                             const float* __restrict__ sdstL,
                                             float* __restrict__ carr){
  const int lane = threadIdx.x & 63;
  const long row = (long)blockIdx.x * 4 + (threadIdx.x >> 6);
  const int b = (int)(row >> 11);
  const float siL = ssrcL[row];
  const float* sd = sdstL + (long)b*2048;
  float mx = -3.4e38f;
#pragma unroll
  for (int k = 0; k < 8; ++k){
    f32x4 v = *(const f32x4*)(sd + lane*4 + k*256);
    mx = fmaxf(mx, fmaxf(fmaxf(v[0], v[1]), fmaxf(v[2], v[3])));
  }
#pragma unroll
  for (int off = 1; off <= 32; off <<= 1) mx = fmaxf(mx, __shfl_xor(mx, off));
  const float mL = lrelu(siL + mx);
  float sum = 0.f;
#pragma unroll
  for (int k = 0; k < 8; ++k){
    f32x4 v = *(const f32x4*)(sd + lane*4 + k*256);
#pragma unroll
    for (int e = 0; e < 4; ++e) sum += fast_exp2(lrelu(siL + v[e]) - mL);
  }
#pragma unroll
  for (int off = 1; off <= 32; off <<= 1) sum += __shfl_xor(sum, off);
  if (lane == 0) carr[row] = mL + __log2f(sum);
}

// ---------------- K3: out = LR( (adj + alpha) @ h ) ----------------
// grid 512 = 8b x 64 tiles (BM=32), 2 blocks/CU with INDEPENDENT barriers.
// block 256 = 4 waves: kh=t>>7 (K-half), wr=(t>>6)&1 (16-row group).
// ht double-buffered in LDS, one raw barrier per K-step; red aliased onto tl.
__global__ __launch_bounds__(256) void k3_main(const float* __restrict__ adj,
                                               const unsigned short* __restrict__ ht,
                                               const float* __restrict__ ssrcL,
                                               const float* __restrict__ sdstL,
                                               const float* __restrict__ carr,
                                               float* __restrict__ out){
  __shared__ __align__(16) char smem[40960];   // tl[2][2][128*40] shorts; red[32*128] f32 aliased
  unsigned short* tl = (unsigned short*)smem;
  float* red = (float*)smem;
  const int t   = threadIdx.x;
  const int bx  = blockIdx.x;
  const int b   = bx >> 6;
  const int i0  = (bx & 63) * 32;
  const int lane = t & 63;
  const int lr  = lane & 15, hi = lane >> 4;
  const int kh  = t >> 7, wr = (t >> 6) & 1;
  const int rowi = i0 + wr*16 + lr;
  const long rowg = (long)b*2048 + rowi;
  const float siL = ssrcL[rowg];
  const float Ci  = carr[rowg];
  const float* adjrow = adj + rowg*2048 + kh*1024 + hi*8;
  const float* sdb    = sdstL + (long)b*2048 + kh*1024 + hi*8;
  const unsigned short* htg = ht + (long)b*262144;
  const int so = t >> 2, sseg = t & 3;                 // staging: o-rows so, so+64; 16B seg
  const unsigned short* sgp0 = htg + (long)so*2048 + sseg*8;
  const unsigned short* sgp1 = htg + (long)(so + 64)*2048 + sseg*8;
  const int woff0 = so*40 + sseg*8;
  const int woff1 = (so + 64)*40 + sseg*8;

  f32x4 zro = {0.f, 0.f, 0.f, 0.f};
  f32x4 acc[8];
#pragma unroll
  for (int i = 0; i < 8; ++i) acc[i] = zro;

  // ---- prologue: tile0 -> buf0; tiles 1,2 -> regs; adj/sd steps 0,1 -> regs ----
  *(int4v*)(tl + 0*5120 + woff0) = *(const int4v*)(sgp0);
  *(int4v*)(tl + 1*5120 + woff0) = *(const int4v*)(sgp0 + 1024);
  *(int4v*)(tl + 0*5120 + woff1) = *(const int4v*)(sgp1);
  *(int4v*)(tl + 1*5120 + woff1) = *(const int4v*)(sgp1 + 1024);
  int4v pA0 = *(const int4v*)(sgp0 + 32);
  int4v pA1 = *(const int4v*)(sgp0 + 1024 + 32);
  int4v pA2 = *(const int4v*)(sgp1 + 32);
  int4v pA3 = *(const int4v*)(sgp1 + 1024 + 32);
  int4v pB0 = *(const int4v*)(sgp0 + 64);
  int4v pB1 = *(const int4v*)(sgp0 + 1024 + 64);
  int4v pB2 = *(const int4v*)(sgp1 + 64);
  int4v pB3 = *(const int4v*)(sgp1 + 1024 + 64);
  f32x4 aA0 = *(const f32x4*)(adjrow);
  f32x4 aA1 = *(const f32x4*)(adjrow + 4);
  f32x4 dA0 = *(const f32x4*)(sdb);
  f32x4 dA1 = *(const f32x4*)(sdb + 4);
  f32x4 aB0 = *(const f32x4*)(adjrow + 32);
  f32x4 aB1 = *(const f32x4*)(adjrow + 36);
  f32x4 dB0 = *(const f32x4*)(sdb + 32);
  f32x4 dB1 = *(const f32x4*)(sdb + 36);
  asm volatile("s_waitcnt lgkmcnt(0)" ::: "memory");
  __builtin_amdgcn_s_barrier();
  __builtin_amdgcn_sched_barrier(0);

#define K3_ITER(KT, P0, P1, P2, P3, A0, A1, D0, D1, BW, BR)  do{                 \
    *(int4v*)(tl + ((BW)*2+0)*5120 + woff0) = P0;   /* write tile KT+1 */        \
    *(int4v*)(tl + ((BW)*2+1)*5120 + woff0) = P1;                                \
    *(int4v*)(tl + ((BW)*2+0)*5120 + woff1) = P2;                                \
    *(int4v*)(tl + ((BW)*2+1)*5120 + woff1) = P3;                                \
    {  const int jo3 = ((KT)+3 < 32 ? (KT)+3 : 31)*32;  /* stage tile KT+3 */    \
       P0 = *(const int4v*)(sgp0 + jo3);                                         \
       P1 = *(const int4v*)(sgp0 + 1024 + jo3);                                  \
       P2 = *(const int4v*)(sgp1 + jo3);                                         \
       P3 = *(const int4v*)(sgp1 + 1024 + jo3); }                                \
    bf16x8 af;                                                                   \
    {  float w[8];                                                               \
       _Pragma("unroll")                                                         \
       for (int e = 0; e < 4; ++e){                                              \
         const float u0 = siL + D0[e];                                           \
         w[e]     = A0[e] + fast_exp2(lrelu(u0) - Ci);                           \
         const float u1 = siL + D1[e];                                           \
         w[4 + e] = A1[e] + fast_exp2(lrelu(u1) - Ci);                           \
       }                                                                         \
       const unsigned int p01 = __builtin_amdgcn_perm(__float_as_uint(w[1]), __float_as_uint(w[0]), 0x07060302u); \
       const unsigned int p23 = __builtin_amdgcn_perm(__float_as_uint(w[3]), __float_as_uint(w[2]), 0x07060302u); \
       const unsigned int p45 = __builtin_amdgcn_perm(__float_as_uint(w[5]), __float_as_uint(w[4]), 0x07060302u); \
       const unsigned int p67 = __builtin_amdgcn_perm(__float_as_uint(w[7]), __float_as_uint(w[6]), 0x07060302u); \
       int4v ai = {(int)p01, (int)p23, (int)p45, (int)p67};                      \
       af = *(bf16x8*)&ai;                                                       \
    }                                                                            \
    {  const int jn = ((KT)+2 < 32 ? (KT)+2 : 31)*32;   /* adj/sd for KT+2 */    \
       A0 = *(const f32x4*)(adjrow + jn);                                        \
       A1 = *(const f32x4*)(adjrow + jn + 4);                                    \
       D0 = *(const f32x4*)(sdb + jn);                                           \
       D1 = *(const f32x4*)(sdb + jn + 4); }                                     \
    __builtin_amdgcn_s_setprio(1);                                               \
    _Pragma("unroll")                                                            \
    for (int cg = 0; cg < 8; ++cg){                                              \
      const bf16x8 bfv = *(const bf16x8*)(tl + ((BR)*2+kh)*5120 + (cg*16 + lr)*40 + hi*8); \
      acc[cg] = __builtin_amdgcn_mfma_f32_16x16x32_bf16(af, bfv, acc[cg], 0, 0, 0); \
    }                                                                            \
    __builtin_amdgcn_s_setprio(0);                                               \
    asm volatile("s_waitcnt lgkmcnt(0)" ::: "memory");                           \
    __builtin_amdgcn_s_barrier();                                                \
    __builtin_amdgcn_sched_barrier(0);                                           \
  }while(0)

  for (int kt = 0; kt < 32; kt += 2){
    K3_ITER(kt,     pA0, pA1, pA2, pA3, aA0, aA1, dA0, dA1, 1, 0);
    K3_ITER(kt + 1, pB0, pB1, pB2, pB3, aB0, aB1, dB0, dB1, 0, 1);
  }
#undef K3_ITER

  // ---- epilogue: split-K reduce (red aliases tl; safe after final barrier) ----
  if (kh == 1){
#pragma unroll
    for (int cg = 0; cg < 8; ++cg)
#pragma unroll
      for (int q = 0; q < 4; ++q)
        red[(wr*16 + hi*4 + q)*128 + cg*16 + lr] = acc[cg][q];
  }
  __syncthreads();
  if (kh == 0){
#pragma unroll
    for (int cg = 0; cg < 8; ++cg){
#pragma unroll
      for (int q = 0; q < 4; ++q){
        const int rl2 = wr*16 + hi*4 + q;
        const float v = acc[cg][q] + red[rl2*128 + cg*16 + lr];
        out[((long)b*2048 + i0 + rl2)*128 + cg*16 + lr] = lrelu(v);
      }
    }
  }
}

extern "C" void kernel_launch(void* const* d_in, const int* in_sizes, int n_in,
                              void* d_out, int out_size, void* d_ws, size_t ws_size,
                              hipStream_t stream){
  const float* x   = (const float*)d_in[0];
  const float* adj = (const float*)d_in[1];
  const float* W   = (const float*)d_in[2];
  const float* a   = (const float*)d_in[3];
  float* out = (float*)d_out;
  char* ws = (char*)d_ws;

  unsigned short* ht    = (unsigned short*)(ws);              // 4 MB
  float*          ssrcL = (float*)(ws + 4194304);             // 64 KB
  float*          sdstL = (float*)(ws + 4259840);             // 64 KB
  float*          carr  = (float*)(ws + 4325376);             // 64 KB
  unsigned short* Wt    = (unsigned short*)(ws + 4390912);    // 32 KB

  k0_wt   <<<1,    256, 0, stream>>>(W, Wt);
  k1_fused<<<512,  256, 0, stream>>>(x, Wt, a, ht, ssrcL, sdstL);
  k2_ml   <<<4096, 256, 0, stream>>>(ssrcL, sdstL, carr);
  k3_main <<<512,  256, 0, stream>>>(adj, ht, ssrcL, sdstL, carr, out);
}

// Round 5
// 63.180 us; speedup vs baseline: 1.0251x; 1.0251x over previous
//
#include <hip/hip_runtime.h>
#include <hip/hip_bf16.h>

#define NEG 0.2f
#define LOG2E 1.4426950408889634f

typedef __attribute__((ext_vector_type(8))) short bf16x8;
typedef __attribute__((ext_vector_type(4))) float f32x4;
typedef __attribute__((ext_vector_type(4))) int int4v;

__device__ __forceinline__ float lrelu(float t){ return fmaxf(t, NEG * t); }
__device__ __forceinline__ float fast_exp2(float x){
  float r; asm("v_exp_f32 %0, %1" : "=v"(r) : "v"(x)); return r;
}
__device__ __forceinline__ unsigned short f2bf(float f){   // RNE
  union { float f; unsigned int u; } v; v.f = f;
  unsigned int r = v.u + 0x7FFFu + ((v.u >> 16) & 1u);
  return (unsigned short)(r >> 16);
}

// ---------------- K0: Wt[o][k] = bf16(W[k][o]), once ----------------
__global__ __launch_bounds__(256) void k0_wt(const float* __restrict__ W,
                                             unsigned short* __restrict__ Wt){
  __shared__ __align__(16) unsigned short wl[128*136];
  const int t = threadIdx.x;
  {
    const int k = t >> 1, oh = (t & 1) * 64;
#pragma unroll 8
    for (int e = 0; e < 64; ++e)
      wl[(oh + e)*136 + k] = f2bf(W[k*128 + oh + e]);
  }
  __syncthreads();
  {
    const int o = t >> 1, ks = (t & 1) * 64;
#pragma unroll
    for (int g = 0; g < 8; ++g){
      int4v v = *(const int4v*)(wl + o*136 + ks + g*8);
      *(int4v*)(Wt + o*128 + ks + g*8) = v;
    }
  }
}

// ---------------- K1: h^T via MFMA + scaled s_src/s_dst + ht store ----------------
__global__ __launch_bounds__(256) void k1_fused(const float* __restrict__ x,
                                                const unsigned short* __restrict__ Wt,
                                                const float* __restrict__ a,
                                                unsigned short* __restrict__ ht,
                                                float* __restrict__ ssrcL,
                                                float* __restrict__ sdstL){
  __shared__ __align__(16) unsigned short wtl[128*136];
  __shared__ __align__(16) unsigned short xl[32*136];
  __shared__ __align__(16) unsigned short tlw[128*34];
  __shared__ float sred[2][4][2][16];
  const int t = threadIdx.x;
  const int bx = blockIdx.x;                 // b*64 + jt
  const int b  = bx >> 6;
  const int jt = bx & 63;
  const long rowbase = (long)bx * 32;
  {
    const int o = t >> 1, seg = (t & 1) * 64;
    const int4v* src = (const int4v*)(Wt + o*128 + seg);
    int4v* dst = (int4v*)(wtl + o*136 + seg);
#pragma unroll
    for (int g = 0; g < 8; ++g) dst[g] = src[g];
  }
  {
    const int i = t >> 3, ks = (t & 7) * 16;
    const f32x4* src = (const f32x4*)(x + (rowbase + i)*128 + ks);
    unsigned int q[8];
#pragma unroll
    for (int g = 0; g < 4; ++g){
      f32x4 v = src[g];
      q[g*2]   = (unsigned)f2bf(v[0]) | ((unsigned)f2bf(v[1]) << 16);
      q[g*2+1] = (unsigned)f2bf(v[2]) | ((unsigned)f2bf(v[3]) << 16);
    }
    int4v* dst = (int4v*)(xl + i*136 + ks);
    dst[0] = *(int4v*)&q[0];
    dst[1] = *(int4v*)&q[4];
  }
  __syncthreads();
  const int w = t >> 6, lane = t & 63, lr = lane & 15, hi = lane >> 4;
  f32x4 zro = {0.f, 0.f, 0.f, 0.f};
  f32x4 acc00 = zro, acc01 = zro, acc10 = zro, acc11 = zro;
#pragma unroll
  for (int ks = 0; ks < 4; ++ks){
    const bf16x8 a0 = *(const bf16x8*)(wtl + (w*32      + lr)*136 + ks*32 + hi*8);
    const bf16x8 a1 = *(const bf16x8*)(wtl + (w*32 + 16 + lr)*136 + ks*32 + hi*8);
    const bf16x8 b0 = *(const bf16x8*)(xl + (     lr)*136 + ks*32 + hi*8);
    const bf16x8 b1 = *(const bf16x8*)(xl + (16 + lr)*136 + ks*32 + hi*8);
    acc00 = __builtin_amdgcn_mfma_f32_16x16x32_bf16(a0, b0, acc00, 0, 0, 0);
    acc01 = __builtin_amdgcn_mfma_f32_16x16x32_bf16(a0, b1, acc01, 0, 0, 0);
    acc10 = __builtin_amdgcn_mfma_f32_16x16x32_bf16(a1, b0, acc10, 0, 0, 0);
    acc11 = __builtin_amdgcn_mfma_f32_16x16x32_bf16(a1, b1, acc11, 0, 0, 0);
  }
  {
    const f32x4 as0 = *(const f32x4*)(a +       w*32      + hi*4);
    const f32x4 as1 = *(const f32x4*)(a +       w*32 + 16 + hi*4);
    const f32x4 ad0 = *(const f32x4*)(a + 128 + w*32      + hi*4);
    const f32x4 ad1 = *(const f32x4*)(a + 128 + w*32 + 16 + hi*4);
    float ps0, ps1, pd0, pd1;
    {
      f32x4 u = acc00*as0 + acc10*as1;  ps0 = u[0]+u[1]+u[2]+u[3];
      f32x4 v = acc01*as0 + acc11*as1;  ps1 = v[0]+v[1]+v[2]+v[3];
      f32x4 p = acc00*ad0 + acc10*ad1;  pd0 = p[0]+p[1]+p[2]+p[3];
      f32x4 r = acc01*ad0 + acc11*ad1;  pd1 = r[0]+r[1]+r[2]+r[3];
    }
#pragma unroll
    for (int off = 16; off <= 32; off <<= 1){
      ps0 += __shfl_xor(ps0, off); ps1 += __shfl_xor(ps1, off);
      pd0 += __shfl_xor(pd0, off); pd1 += __shfl_xor(pd1, off);
    }
    if (hi == 0){
      sred[0][w][0][lr] = ps0; sred[0][w][1][lr] = ps1;
      sred[1][w][0][lr] = pd0; sred[1][w][1][lr] = pd1;
    }
  }
#pragma unroll
  for (int q = 0; q < 4; ++q){
    tlw[(w*32      + hi*4 + q)*34      + lr] = f2bf(acc00[q]);
    tlw[(w*32      + hi*4 + q)*34 + 16 + lr] = f2bf(acc01[q]);
    tlw[(w*32 + 16 + hi*4 + q)*34      + lr] = f2bf(acc10[q]);
    tlw[(w*32 + 16 + hi*4 + q)*34 + 16 + lr] = f2bf(acc11[q]);
  }
  __syncthreads();
  {
    const int o = t >> 1, jseg = (t & 1) * 16;
    const unsigned int* src = (const unsigned int*)(tlw + o*34 + jseg);
    unsigned int p[8];
#pragma unroll
    for (int g = 0; g < 8; ++g) p[g] = src[g];
    unsigned short* dst = ht + (long)b*262144 + (long)o*2048 + jt*32 + jseg;
    ((int4v*)dst)[0] = *(int4v*)&p[0];
    ((int4v*)dst)[1] = *(int4v*)&p[4];
  }
  if (t < 64){
    const int sel = t >> 5, jl = t & 31;
    const int ig = jl >> 4, l2 = jl & 15;
    const float s = sred[sel][0][ig][l2] + sred[sel][1][ig][l2]
                  + sred[sel][2][ig][l2] + sred[sel][3][ig][l2];
    if (sel == 0) ssrcL[rowbase + jl] = s * LOG2E;
    else          sdstL[rowbase + jl] = s * LOG2E;
  }
}

// ---------------- K2: per-row C_i = m_L + log2(sum_j 2^(lrelu(siL+sjL)-m_L)) ----------------
__global__ __launch_bounds__(256) void k2_ml(const float* __restrict__ ssrcL,
                                             const float* __restrict__ sdstL,
                                             float* __restrict__ carr){
  const int lane = threadIdx.x & 63;
  const long row = (long)blockIdx.x * 4 + (threadIdx.x >> 6);
  const int b = (int)(row >> 11);
  const float siL = ssrcL[row];
  const float* sd = sdstL + (long)b*2048;
  float mx = -3.4e38f;
#pragma unroll
  for (int k = 0; k < 8; ++k){
    f32x4 v = *(const f32x4*)(sd + lane*4 + k*256);
    mx = fmaxf(mx, fmaxf(fmaxf(v[0], v[1]), fmaxf(v[2], v[3])));
  }
#pragma unroll
  for (int off = 1; off <= 32; off <<= 1) mx = fmaxf(mx, __shfl_xor(mx, off));
  const float mL = lrelu(siL + mx);
  float sum = 0.f;
#pragma unroll
  for (int k = 0; k < 8; ++k){
    f32x4 v = *(const f32x4*)(sd + lane*4 + k*256);
#pragma unroll
    for (int e = 0; e < 4; ++e) sum += fast_exp2(lrelu(siL + v[e]) - mL);
  }
#pragma unroll
  for (int off = 1; off <= 32; off <<= 1) sum += __shfl_xor(sum, off);
  if (lane == 0) carr[row] = mL + __log2f(sum);
}

// ---------------- K3: out = LR( (adj + alpha) @ h ) ----------------
// grid 512 = 8b x 64 tiles (BM=32), XCD-swizzled so batch b lives on XCD b.
// block 256 = 4 waves (kh K-half, wr 16-row group); 2 blocks/CU (launch_bounds(256,2)
// -> 256-VGPR budget so the software pipeline STAYS IN REGISTERS).
// ht double-buffered in LDS (lead 2); adj/sdst quad-buffered regs (lead 4 > HBM latency).
__global__ __launch_bounds__(256, 2) void k3_main(const float* __restrict__ adj,
                                                  const unsigned short* __restrict__ ht,
                                                  const float* __restrict__ ssrcL,
                                                  const float* __restrict__ sdstL,
                                                  const float* __restrict__ carr,
                                                  float* __restrict__ out){
  __shared__ __align__(16) char smem[40960];   // tl[2][2][128*40] shorts; red[32*128] f32 aliased
  unsigned short* tl = (unsigned short*)smem;
  float* red = (float*)smem;
  const int t   = threadIdx.x;
  const int bxr = blockIdx.x;
  const int bx  = ((bxr & 7) << 6) | (bxr >> 3);   // XCD swizzle: batch -> one XCD's L2
  const int b   = bx >> 6;
  const int i0  = (bx & 63) * 32;
  const int lane = t & 63;
  const int lr  = lane & 15, hi = lane >> 4;
  const int kh  = t >> 7, wr = (t >> 6) & 1;
  const int rowi = i0 + wr*16 + lr;
  const long rowg = (long)b*2048 + rowi;
  const float siL = ssrcL[rowg];
  const float Ci  = carr[rowg];
  const float* adjrow = adj + rowg*2048 + kh*1024 + hi*8;
  const float* sdb    = sdstL + (long)b*2048 + kh*1024 + hi*8;
  const unsigned short* htg = ht + (long)b*262144;
  const int so = t >> 2, sseg = t & 3;
  const unsigned short* sgp0 = htg + (long)so*2048 + sseg*8;
  const unsigned short* sgp1 = htg + (long)(so + 64)*2048 + sseg*8;
  const int woff0 = so*40 + sseg*8;
  const int woff1 = (so + 64)*40 + sseg*8;

  f32x4 zro = {0.f, 0.f, 0.f, 0.f};
  f32x4 acc[8];
#pragma unroll
  for (int i = 0; i < 8; ++i) acc[i] = zro;

  // ---- prologue ----
  // tile 0 -> LDS buf0 directly
  *(int4v*)(tl + 0*5120 + woff0) = *(const int4v*)(sgp0);
  *(int4v*)(tl + 1*5120 + woff0) = *(const int4v*)(sgp0 + 1024);
  *(int4v*)(tl + 0*5120 + woff1) = *(const int4v*)(sgp1);
  *(int4v*)(tl + 1*5120 + woff1) = *(const int4v*)(sgp1 + 1024);
  // ht reg sets: HA = tile1, HB = tile2
  int4v hA0 = *(const int4v*)(sgp0 + 32);
  int4v hA1 = *(const int4v*)(sgp0 + 1024 + 32);
  int4v hA2 = *(const int4v*)(sgp1 + 32);
  int4v hA3 = *(const int4v*)(sgp1 + 1024 + 32);
  int4v hB0 = *(const int4v*)(sgp0 + 64);
  int4v hB1 = *(const int4v*)(sgp0 + 1024 + 64);
  int4v hB2 = *(const int4v*)(sgp1 + 64);
  int4v hB3 = *(const int4v*)(sgp1 + 1024 + 64);
  // adj/sdst quad reg sets: steps 0..3
  f32x4 aA0 = *(const f32x4*)(adjrow);        f32x4 aA1 = *(const f32x4*)(adjrow + 4);
  f32x4 dA0 = *(const f32x4*)(sdb);           f32x4 dA1 = *(const f32x4*)(sdb + 4);
  f32x4 aB0 = *(const f32x4*)(adjrow + 32);   f32x4 aB1 = *(const f32x4*)(adjrow + 36);
  f32x4 dB0 = *(const f32x4*)(sdb + 32);      f32x4 dB1 = *(const f32x4*)(sdb + 36);
  f32x4 aC0 = *(const f32x4*)(adjrow + 64);   f32x4 aC1 = *(const f32x4*)(adjrow + 68);
  f32x4 dC0 = *(const f32x4*)(sdb + 64);      f32x4 dC1 = *(const f32x4*)(sdb + 68);
  f32x4 aD0 = *(const f32x4*)(adjrow + 96);   f32x4 aD1 = *(const f32x4*)(adjrow + 100);
  f32x4 dD0 = *(const f32x4*)(sdb + 96);      f32x4 dD1 = *(const f32x4*)(sdb + 100);
  asm volatile("s_waitcnt lgkmcnt(0)" ::: "memory");
  __builtin_amdgcn_s_barrier();
  __builtin_amdgcn_sched_barrier(0);

#define K3_ITER(KT, P0, P1, P2, P3, A0, A1, D0, D1, BW, BR)  do{                 \
    *(int4v*)(tl + ((BW)*2+0)*5120 + woff0) = P0;   /* publish tile KT+1 */      \
    *(int4v*)(tl + ((BW)*2+1)*5120 + woff0) = P1;                                \
    *(int4v*)(tl + ((BW)*2+0)*5120 + woff1) = P2;                                \
    *(int4v*)(tl + ((BW)*2+1)*5120 + woff1) = P3;                                \
    {  const int j3 = ((KT)+3 < 32 ? (KT)+3 : 31)*32;  /* ht tile KT+3 */        \
       P0 = *(const int4v*)(sgp0 + j3);                                          \
       P1 = *(const int4v*)(sgp0 + 1024 + j3);                                   \
       P2 = *(const int4v*)(sgp1 + j3);                                          \
       P3 = *(const int4v*)(sgp1 + 1024 + j3); }                                 \
    bf16x8 af;                                                                   \
    {  float w[8];                                                               \
       _Pragma("unroll")                                                         \
       for (int e = 0; e < 4; ++e){                                              \
         const float u0 = siL + D0[e];                                           \
         w[e]     = A0[e] + fast_exp2(lrelu(u0) - Ci);                           \
         const float u1 = siL + D1[e];                                           \
         w[4 + e] = A1[e] + fast_exp2(lrelu(u1) - Ci);                           \
       }                                                                         \
       const unsigned int p01 = __builtin_amdgcn_perm(__float_as_uint(w[1]), __float_as_uint(w[0]), 0x07060302u); \
       const unsigned int p23 = __builtin_amdgcn_perm(__float_as_uint(w[3]), __float_as_uint(w[2]), 0x07060302u); \
       const unsigned int p45 = __builtin_amdgcn_perm(__float_as_uint(w[5]), __float_as_uint(w[4]), 0x07060302u); \
       const unsigned int p67 = __builtin_amdgcn_perm(__float_as_uint(w[7]), __float_as_uint(w[6]), 0x07060302u); \
       int4v ai = {(int)p01, (int)p23, (int)p45, (int)p67};                      \
       af = *(bf16x8*)&ai;                                                       \
    }                                                                            \
    {  const int j4 = ((KT)+4 < 32 ? (KT)+4 : 31)*32;   /* adj/sd step KT+4 */   \
       A0 = *(const f32x4*)(adjrow + j4);                                        \
       A1 = *(const f32x4*)(adjrow + j4 + 4);                                    \
       D0 = *(const f32x4*)(sdb + j4);                                           \
       D1 = *(const f32x4*)(sdb + j4 + 4); }                                     \
    __builtin_amdgcn_s_setprio(1);                                               \
    _Pragma("unroll")                                                            \
    for (int cg = 0; cg < 8; ++cg){                                              \
      const bf16x8 bfv = *(const bf16x8*)(tl + ((BR)*2+kh)*5120 + (cg*16 + lr)*40 + hi*8); \
      acc[cg] = __builtin_amdgcn_mfma_f32_16x16x32_bf16(af, bfv, acc[cg], 0, 0, 0); \
    }                                                                            \
    __builtin_amdgcn_s_setprio(0);                                               \
    asm volatile("s_waitcnt lgkmcnt(0)" ::: "memory");                           \
    __builtin_amdgcn_s_barrier();                                                \
    __builtin_amdgcn_sched_barrier(0);                                           \
  }while(0)

  for (int kt = 0; kt < 32; kt += 4){
    K3_ITER(kt,     hA0, hA1, hA2, hA3, aA0, aA1, dA0, dA1, 1, 0);
    K3_ITER(kt + 1, hB0, hB1, hB2, hB3, aB0, aB1, dB0, dB1, 0, 1);
    K3_ITER(kt + 2, hA0, hA1, hA2, hA3, aC0, aC1, dC0, dC1, 1, 0);
    K3_ITER(kt + 3, hB0, hB1, hB2, hB3, aD0, aD1, dD0, dD1, 0, 1);
  }
#undef K3_ITER

  // ---- epilogue: split-K reduce (red aliases tl; safe after final barrier) ----
  if (kh == 1){
#pragma unroll
    for (int cg = 0; cg < 8; ++cg)
#pragma unroll
      for (int q = 0; q < 4; ++q)
        red[(wr*16 + hi*4 + q)*128 + cg*16 + lr] = acc[cg][q];
  }
  __syncthreads();
  if (kh == 0){
#pragma unroll
    for (int cg = 0; cg < 8; ++cg){
#pragma unroll
      for (int q = 0; q < 4; ++q){
        const int rl2 = wr*16 + hi*4 + q;
        const float v = acc[cg][q] + red[rl2*128 + cg*16 + lr];
        out[((long)b*2048 + i0 + rl2)*128 + cg*16 + lr] = lrelu(v);
      }
    }
  }
}

extern "C" void kernel_launch(void* const* d_in, const int* in_sizes, int n_in,
                              void* d_out, int out_size, void* d_ws, size_t ws_size,
                              hipStream_t stream){
  const float* x   = (const float*)d_in[0];
  const float* adj = (const float*)d_in[1];
  const float* W   = (const float*)d_in[2];
  const float* a   = (const float*)d_in[3];
  float* out = (float*)d_out;
  char* ws = (char*)d_ws;

  unsigned short* ht    = (unsigned short*)(ws);              // 4 MB
  float*          ssrcL = (float*)(ws + 4194304);             // 64 KB
  float*          sdstL = (float*)(ws + 4259840);             // 64 KB
  float*          carr  = (float*)(ws + 4325376);             // 64 KB
  unsigned short* Wt    = (unsigned short*)(ws + 4390912);    // 32 KB

  k0_wt   <<<1,    256, 0, stream>>>(W, Wt);
  k1_fused<<<512,  256, 0, stream>>>(x, Wt, a, ht, ssrcL, sdstL);
  k2_ml   <<<4096, 256, 0, stream>>>(ssrcL, sdstL, carr);
  k3_main <<<512,  256, 0, stream>>>(adj, ht, ssrcL, sdstL, carr, out);
}